// Round 3
// baseline (7552.342 us; speedup 1.0000x reference)
//
#include <hip/hip_runtime.h>

#define NEG_FILL (-65535.0f)   // -2^16 + 1, the mask fill value

// ---------------------------------------------------------------------------
// Copy 4096 floats (the [1,8,512] B matrix). grid = 16 x 256.
__global__ __launch_bounds__(256) void k_copy4k(const float* __restrict__ src,
                                                float* __restrict__ dst) {
    int i = blockIdx.x * 256 + threadIdx.x;
    dst[i] = src[i];
}

// ---------------------------------------------------------------------------
// One routing iteration, DIRECT form (mirrors the reference dataflow).
// One block per batch element. 256 threads = 4 waves; wave g, lane o.
// low_new rows are recomputed on the fly: ln[o] = sum_d low[b,l,d]*S[d,o],
// with low[b,l,d] broadcast across the wave via __shfl (wave-safe, no LDS
// write/read races).
__global__ __launch_bounds__(256) void k_route(
    const float* __restrict__ low,     // [1024,512,64] f32
    const float* __restrict__ S,       // [64,64] f32
    const float* __restrict__ Bcur,    // [8,512] f32
    float* __restrict__ Bnext,         // [8,512] f32 (atomic accum), if !last
    const int* __restrict__ seq_len,   // [1024] i32
    float* __restrict__ out,           // [1024,8,64] f32, used only if last
    int last)
{
    __shared__ float St[64][64];      // St[d][o] = S[d*64+o]  (natural layout)
    __shared__ float Ws[8][512];      // W[k][l]
    __shared__ float Tpart[4][8][64]; // per-wave partial T
    __shared__ float Tred[8][64];     // reduced T, then squashed high

    const int t  = threadIdx.x;
    const int o  = t & 63;            // lane
    const int g  = t >> 6;            // wave 0..3
    const int b  = blockIdx.x;
    const int sl = seq_len[b];
    const float* lowb = low + ((size_t)b << 15);   // b*512*64

    // ---- stage S (natural layout, coalesced) ------------------------------
    #pragma unroll
    for (int i = 0; i < 16; ++i) {
        int idx = t + (i << 8);                  // 0..4095
        St[idx >> 6][idx & 63] = S[idx];         // St[d][o] = S[d][o]
    }

    // ---- masked softmax over l, wave-local; wave g owns k=g and k=g+4 -----
    #pragma unroll
    for (int kk = 0; kk < 2; ++kk) {
        const int k = g + (kk << 2);
        float v[8];
        float m = NEG_FILL;
        #pragma unroll
        for (int j = 0; j < 8; ++j) {
            int l = o + (j << 6);
            v[j] = (l < sl) ? Bcur[(k << 9) + l] : NEG_FILL;
            m = fmaxf(m, v[j]);
        }
        #pragma unroll
        for (int off = 32; off; off >>= 1) m = fmaxf(m, __shfl_xor(m, off));
        float s = 0.f;
        #pragma unroll
        for (int j = 0; j < 8; ++j) { v[j] = expf(v[j] - m); s += v[j]; }
        #pragma unroll
        for (int off = 32; off; off >>= 1) s += __shfl_xor(s, off);
        const float inv = 1.0f / s;
        #pragma unroll
        for (int j = 0; j < 8; ++j) Ws[k][o + (j << 6)] = v[j] * inv;
    }
    __syncthreads();

    // ---- pass 1: T[k][o] = sum_l W[k][l]*low_new[l][o], l === g (mod 4) ---
    float Ta[8];
    #pragma unroll
    for (int k = 0; k < 8; ++k) Ta[k] = 0.f;

    for (int i = 0; i < 128; ++i) {
        const int l = g + (i << 2);
        const float xo = lowb[(l << 6) + o];     // low[b][l][o], coalesced
        float ln = 0.f;                          // low_new[b][l][o]
        #pragma unroll
        for (int d = 0; d < 64; ++d)
            ln = fmaf(__shfl(xo, d), St[d][o], ln);
        #pragma unroll
        for (int k = 0; k < 8; ++k)
            Ta[k] = fmaf(Ws[k][l], ln, Ta[k]);
    }
    #pragma unroll
    for (int k = 0; k < 8; ++k) Tpart[g][k][o] = Ta[k];
    __syncthreads();

    // ---- reduce partials over the 4 waves; thread keeps k=g and k=g+4 -----
    float h0 = 0.f, h1 = 0.f;
    #pragma unroll
    for (int gg = 0; gg < 4; ++gg) {
        h0 += Tpart[gg][g][o];
        h1 += Tpart[gg][g + 4][o];
    }
    Tred[g][o]     = h0;
    Tred[g + 4][o] = h1;
    __syncthreads();

    // ---- squash over K (axis=1 of [B,K,D]): per column o ------------------
    float sq = 0.f;
    #pragma unroll
    for (int k = 0; k < 8; ++k) { float x = Tred[k][o]; sq = fmaf(x, x, sq); }
    const float scale = sq / (1.0f + sq) / sqrtf(sq + 1e-9f);
    const float hf0 = scale * h0;
    const float hf1 = scale * h1;

    if (last) {
        out[(((size_t)b * 8 + g)     << 6) + o] = hf0;
        out[(((size_t)b * 8 + g + 4) << 6) + o] = hf1;
        return;
    }

    __syncthreads();                 // all squash reads of Tred done
    Tred[g][o]     = hf0;            // Tred now holds squashed high
    Tred[g + 4][o] = hf1;
    __syncthreads();

    // ---- pass 2: delta[k][l] = sum_o high[k][o]*low_new[l][o] -------------
    for (int i = 0; i < 128; ++i) {
        const int l = g + (i << 2);
        const float xo = lowb[(l << 6) + o];
        float ln = 0.f;
        #pragma unroll
        for (int d = 0; d < 64; ++d)
            ln = fmaf(__shfl(xo, d), St[d][o], ln);
        #pragma unroll
        for (int k = 0; k < 8; ++k) {
            float p = Tred[k][o] * ln;
            #pragma unroll
            for (int off = 32; off; off >>= 1) p += __shfl_xor(p, off);
            if (o == 0) atomicAdd(&Bnext[(k << 9) + l], p);
        }
    }
}

// ---------------------------------------------------------------------------
extern "C" void kernel_launch(void* const* d_in, const int* in_sizes, int n_in,
                              void* d_out, int out_size, void* d_ws, size_t ws_size,
                              hipStream_t stream) {
    const float* low   = (const float*)d_in[0];   // [1024,512,64]
    const float* Binit = (const float*)d_in[1];   // [1,8,512]
    const float* S     = (const float*)d_in[2];   // [64,64]
    const int*   seq   = (const int*)d_in[3];     // [1024,1]

    float* outp = (float*)d_out;                  // [1024,8,64] f32
    float* B0 = (float*)d_ws;                     // [8,512]
    float* B1 = B0 + 4096;                        // [8,512]

    const int BATCH = 1024;

    // B0 = B_init
    k_copy4k<<<16, 256, 0, stream>>>(Binit, B0);

    // iteration 0: read B0, accumulate delta into B1 (B1 = B0 + sum_b delta)
    k_copy4k<<<16, 256, 0, stream>>>(B0, B1);
    k_route<<<BATCH, 256, 0, stream>>>(low, S, B0, B1, seq, outp, 0);

    // iteration 1: read B1, accumulate into B0
    k_copy4k<<<16, 256, 0, stream>>>(B1, B0);
    k_route<<<BATCH, 256, 0, stream>>>(low, S, B1, B0, seq, outp, 0);

    // iteration 2 (last): read B0, write output
    k_route<<<BATCH, 256, 0, stream>>>(low, S, B0, nullptr, seq, outp, 1);
}

// Round 4
// 453.054 us; speedup vs baseline: 16.6698x; 16.6698x over previous
//
#include <hip/hip_runtime.h>

#define NEG_FILL (-65535.0f)   // -2^16 + 1, the mask fill value

// ---------------------------------------------------------------------------
// Copy 4096 floats (the [1,8,512] B matrix). grid = 16 x 256.
__global__ __launch_bounds__(256) void k_copy4k(const float* __restrict__ src,
                                                float* __restrict__ dst) {
    int i = blockIdx.x * 256 + threadIdx.x;
    dst[i] = src[i];
}

// ---------------------------------------------------------------------------
// One routing iteration, fused algebra (verified equivalent to reference):
//   W      = softmax(mask ? Bcur : NEG)            [8,512]
//   T[k,d] = sum_l W[k,l]*low[b,l,d]               (W @ low)
//   high   = squash_overK(T @ S)                   [8,64]
//   G[k,d] = sum_o high[k,o]*S[d,o]                (high @ S^T)
//   delta  = G @ low^T -> atomicAdd into Bnext     [8,512]
// One block per batch element; 256 thr = 4 waves. Wave g, lane o.
// Coverage: pass A — wave g owns l in [128g,128g+128), ALL 8 k (partials
// reduced via LDS). Delta — chunk c covers l in [64c,64c+64); thread (g,o)
// covers (k=g, l=64c+o) and (k=g+4, l=64c+o): full (k,l) coverage.
__global__ __launch_bounds__(256, 4) void k_route(
    const float* __restrict__ low,     // [1024,512,64] f32
    const float* __restrict__ S,       // [64,64] f32
    const float* __restrict__ Bcur,    // [8,512] f32
    float* __restrict__ Bnext,         // [8,512] f32 (atomic accum), if !last
    const int* __restrict__ seq_len,   // [1024] i32
    float* __restrict__ out,           // [1024,8,64] f32, used only if last
    int last)
{
    // smemA lifetimes (sync-separated): WsT[512][8] (softmax -> pass A)
    //   -> Tpart[4][8][64] (pass-A reduce) -> tile[64][65] (delta chunks)
    __shared__ float smemA[64 * 65];         // 4160 words = 16640 B
    __shared__ float Spad[64][65];           // S natural, pad 65: both access
                                             // patterns conflict-free
    __shared__ float GT[64][8];              // G transposed: GT[d][k]
    __shared__ float Tred[8][64];            // T, then high_pre, then high

    float* WsT = smemA;                               // [512][8]
    float (*Tpart)[8][64] = (float (*)[8][64])smemA;  // [4][8][64]
    float (*tile)[65]     = (float (*)[65])smemA;     // [64][65]

    const int t  = threadIdx.x;
    const int o  = t & 63;            // lane
    const int g  = t >> 6;            // wave 0..3
    const int b  = blockIdx.x;
    const int sl = seq_len[b];
    const float* lowb = low + ((size_t)b << 15);   // b*512*64

    // ---- stage S: Spad[d][o] = S[d*64+o] (coalesced, conflict-free) -------
    #pragma unroll
    for (int i = 0; i < 16; ++i) {
        int idx = t + (i << 8);                  // 0..4095
        Spad[idx >> 6][idx & 63] = S[idx];
    }

    // ---- masked softmax over l, wave-local; wave g owns k=g and k=g+4 -----
    #pragma unroll
    for (int kk = 0; kk < 2; ++kk) {
        const int k = g + (kk << 2);
        float v[8];
        float m = NEG_FILL;
        #pragma unroll
        for (int j = 0; j < 8; ++j) {
            int l = o + (j << 6);
            v[j] = (l < sl) ? Bcur[(k << 9) + l] : NEG_FILL;
            m = fmaxf(m, v[j]);
        }
        #pragma unroll
        for (int off = 32; off; off >>= 1) m = fmaxf(m, __shfl_xor(m, off));
        float s = 0.f;
        #pragma unroll
        for (int j = 0; j < 8; ++j) { v[j] = expf(v[j] - m); s += v[j]; }
        #pragma unroll
        for (int off = 32; off; off >>= 1) s += __shfl_xor(s, off);
        const float inv = 1.0f / s;
        #pragma unroll
        for (int j = 0; j < 8; ++j)
            WsT[((o + (j << 6)) << 3) + k] = v[j] * inv;   // WsT[l][k]
    }
    __syncthreads();

    // ---- pass A: Ta[k] = sum_{l in my 128 rows} W[k][l]*low[l][o] ---------
    float Ta[8];
    #pragma unroll
    for (int k = 0; k < 8; ++k) Ta[k] = 0.f;
    {
        const int l0 = g << 7;
        #pragma unroll 4
        for (int i = 0; i < 128; ++i) {
            const int l = l0 + i;
            const float x = lowb[(l << 6) + o];        // coalesced
            const float4 wa = *(const float4*)&WsT[(l << 3)];     // b128 bcast
            const float4 wb = *(const float4*)&WsT[(l << 3) + 4];
            Ta[0] = fmaf(wa.x, x, Ta[0]);
            Ta[1] = fmaf(wa.y, x, Ta[1]);
            Ta[2] = fmaf(wa.z, x, Ta[2]);
            Ta[3] = fmaf(wa.w, x, Ta[3]);
            Ta[4] = fmaf(wb.x, x, Ta[4]);
            Ta[5] = fmaf(wb.y, x, Ta[5]);
            Ta[6] = fmaf(wb.z, x, Ta[6]);
            Ta[7] = fmaf(wb.w, x, Ta[7]);
        }
    }
    __syncthreads();                   // all waves done READING WsT (union!)
    #pragma unroll
    for (int k = 0; k < 8; ++k) Tpart[g][k][o] = Ta[k];
    __syncthreads();

    // ---- reduce partials; thread keeps k=g and k=g+4 (lane o = d) ---------
    float h0 = 0.f, h1 = 0.f;
    #pragma unroll
    for (int gg = 0; gg < 4; ++gg) {
        h0 += Tpart[gg][g][o];
        h1 += Tpart[gg][g + 4][o];
    }
    Tred[g][o]     = h0;               // T[k][d]
    Tred[g + 4][o] = h1;
    __syncthreads();

    // ---- high_pre[k][o] = sum_d T[k][d]*S[d][o] ---------------------------
    float hp0 = 0.f, hp1 = 0.f;
    #pragma unroll
    for (int d = 0; d < 64; ++d) {
        const float sv = Spad[d][o];               // conflict-free
        hp0 = fmaf(Tred[g][d],     sv, hp0);       // broadcast reads
        hp1 = fmaf(Tred[g + 4][d], sv, hp1);
    }
    __syncthreads();                   // done reading Tred (=T)
    Tred[g][o]     = hp0;
    Tred[g + 4][o] = hp1;
    __syncthreads();

    // ---- squash over K (axis=1): per output column o ----------------------
    float sq = 0.f;
    #pragma unroll
    for (int k = 0; k < 8; ++k) { float x = Tred[k][o]; sq = fmaf(x, x, sq); }
    const float scale = sq / (1.0f + sq) / sqrtf(sq + 1e-9f);
    const float hf0 = scale * hp0;
    const float hf1 = scale * hp1;

    if (last) {
        out[(((size_t)b * 8 + g)     << 6) + o] = hf0;
        out[(((size_t)b * 8 + g + 4) << 6) + o] = hf1;
        return;
    }

    __syncthreads();                   // squash reads of Tred done
    Tred[g][o]     = hf0;              // Tred now holds squashed high
    Tred[g + 4][o] = hf1;
    __syncthreads();

    // ---- G[k][d] = sum_oo high[k][oo]*S[d][oo]; lane o = d ----------------
    float g0 = 0.f, g1 = 0.f;
    #pragma unroll
    for (int oo = 0; oo < 64; ++oo) {
        const float sv = Spad[o][oo];              // 2 lanes/bank: free
        g0 = fmaf(Tred[g][oo],     sv, g0);        // broadcast reads
        g1 = fmaf(Tred[g + 4][oo], sv, g1);
    }
    GT[o][g]     = g0;                 // GT[d][k]
    GT[o][g + 4] = g1;
    __syncthreads();                   // GT ready; also done reading smemA

    // ---- delta chunks: tile-transpose low through LDS, lane o = local l ---
    for (int c = 0; c < 8; ++c) {
        const int lc = c << 6;
        #pragma unroll
        for (int r = 0; r < 16; ++r) {
            const int lr = (g << 4) + r;           // wave g loads 16 rows
            tile[lr][o] = lowb[((lc + lr) << 6) + o];   // coalesced
        }
        __syncthreads();
        float a0 = 0.f, a1 = 0.f;
        #pragma unroll
        for (int d = 0; d < 64; ++d) {
            const float x = tile[o][d];            // pad-65: conflict-free
            a0 = fmaf(GT[d][g],     x, a0);        // broadcast reads
            a1 = fmaf(GT[d][g + 4], x, a1);
        }
        atomicAdd(&Bnext[(g << 9)       + lc + o], a0);
        atomicAdd(&Bnext[((g + 4) << 9) + lc + o], a1);
        __syncthreads();               // tile reuse barrier
    }
}

// ---------------------------------------------------------------------------
extern "C" void kernel_launch(void* const* d_in, const int* in_sizes, int n_in,
                              void* d_out, int out_size, void* d_ws, size_t ws_size,
                              hipStream_t stream) {
    const float* low   = (const float*)d_in[0];   // [1024,512,64]
    const float* Binit = (const float*)d_in[1];   // [1,8,512]
    const float* S     = (const float*)d_in[2];   // [64,64]
    const int*   seq   = (const int*)d_in[3];     // [1024,1]

    float* outp = (float*)d_out;                  // [1024,8,64] f32
    float* B0 = (float*)d_ws;                     // [8,512]
    float* B1 = B0 + 4096;                        // [8,512]

    const int BATCH = 1024;

    // B0 = B_init
    k_copy4k<<<16, 256, 0, stream>>>(Binit, B0);

    // iteration 0: read B0, accumulate delta into B1 (B1 = B0 + sum_b delta)
    k_copy4k<<<16, 256, 0, stream>>>(B0, B1);
    k_route<<<BATCH, 256, 0, stream>>>(low, S, B0, B1, seq, outp, 0);

    // iteration 1: read B1, accumulate into B0
    k_copy4k<<<16, 256, 0, stream>>>(B1, B0);
    k_route<<<BATCH, 256, 0, stream>>>(low, S, B1, B0, seq, outp, 0);

    // iteration 2 (last): read B0, write output
    k_route<<<BATCH, 256, 0, stream>>>(low, S, B0, nullptr, seq, outp, 1);
}

// Round 5
// 334.651 us; speedup vs baseline: 22.5678x; 1.3538x over previous
//
#include <hip/hip_runtime.h>

#define NEG_FILL (-65535.0f)   // -2^16 + 1, the mask fill value

typedef __attribute__((ext_vector_type(8))) short  short8;   // 8 x bf16 bits
typedef __attribute__((ext_vector_type(4))) float  floatx4;  // mfma acc

__device__ inline unsigned short f2bf(float f) {             // f32 -> bf16 RNE
    unsigned u = __float_as_uint(f);
    u += 0x7FFFu + ((u >> 16) & 1u);
    return (unsigned short)(u >> 16);
}

// ---------------------------------------------------------------------------
__global__ __launch_bounds__(256) void k_copy4k(const float* __restrict__ src,
                                                float* __restrict__ dst) {
    int i = blockIdx.x * 256 + threadIdx.x;
    dst[i] = src[i];
}

// ---------------------------------------------------------------------------
// Precompute ln[b,l,o] = sum_d low[b,l,d]*S[d,o], stored bf16. MFMA 16x16x32.
// Block = b (512 rows); wave g: rows 128g..128g+127, 8 tiles of 16 rows.
__global__ __launch_bounds__(256, 4) void k_ln(
    const float* __restrict__ low,       // [1024,512,64]
    const float* __restrict__ S,         // [64,64]
    unsigned short* __restrict__ ln)     // [1024,512,64] bf16 out
{
    const int t = threadIdx.x, lane = t & 63, g = t >> 6, b = blockIdx.x;
    const int m = lane & 15, q = lane >> 4;
    const float* lowb = low + ((size_t)b << 15);
    unsigned short* lnb = ln + ((size_t)b << 15);

    // B-frags for S: nt (n-tile of 16 o's) x dh (K-half of 32 d's).
    // B[k=d][n=o]: lane holds col o = nt*16+m, d = dh*32 + q*8 + j.
    short8 sfrag[4][2];
    #pragma unroll
    for (int nt = 0; nt < 4; ++nt)
        #pragma unroll
        for (int dh = 0; dh < 2; ++dh) {
            short8 f;
            #pragma unroll
            for (int j = 0; j < 8; ++j) {
                int d = dh * 32 + q * 8 + j;
                f[j] = (short)f2bf(S[(d << 6) + nt * 16 + m]);
            }
            sfrag[nt][dh] = f;
        }

    #pragma unroll 2
    for (int tt = 0; tt < 8; ++tt) {
        const int lt = (g << 7) + (tt << 4);
        // A-frags: A[m=l][k=d]: lane m -> row lt+m, d = dh*32 + q*8 + 0..7
        short8 afrag[2];
        #pragma unroll
        for (int dh = 0; dh < 2; ++dh) {
            const float4* p =
                (const float4*)&lowb[((lt + m) << 6) + dh * 32 + q * 8];
            float4 x0 = p[0], x1 = p[1];
            short8 f;
            f[0] = (short)f2bf(x0.x); f[1] = (short)f2bf(x0.y);
            f[2] = (short)f2bf(x0.z); f[3] = (short)f2bf(x0.w);
            f[4] = (short)f2bf(x1.x); f[5] = (short)f2bf(x1.y);
            f[6] = (short)f2bf(x1.z); f[7] = (short)f2bf(x1.w);
            afrag[dh] = f;
        }
        #pragma unroll
        for (int nt = 0; nt < 4; ++nt) {
            floatx4 acc = {0.f, 0.f, 0.f, 0.f};
            acc = __builtin_amdgcn_mfma_f32_16x16x32_bf16(afrag[0], sfrag[nt][0], acc, 0, 0, 0);
            acc = __builtin_amdgcn_mfma_f32_16x16x32_bf16(afrag[1], sfrag[nt][1], acc, 0, 0, 0);
            // C: col = m (o-within-tile), row = q*4 + r (l-within-tile)
            #pragma unroll
            for (int r = 0; r < 4; ++r)
                lnb[((size_t)(lt + q * 4 + r) << 6) + nt * 16 + m] = f2bf(acc[r]);
        }
    }
}

// ---------------------------------------------------------------------------
// One routing iteration on precomputed ln (bf16):
//   W = softmax(mask ? Bcur : NEG); T = W @ ln  (== high_pre);
//   high = squash_overK(T); delta = high @ ln^T -> atomicAdd Bnext.
__global__ __launch_bounds__(256, 4) void k_route2(
    const unsigned short* __restrict__ ln,   // [1024,512,64] bf16
    const float* __restrict__ Bcur,          // [8,512]
    float* __restrict__ Bnext,               // [8,512], if !last
    const int* __restrict__ seq_len,         // [1024]
    float* __restrict__ out,                 // [1024,8,64] f32, if last
    int last)
{
    __shared__ __align__(16) float WsT[512][8];        // W transposed
    __shared__ __align__(16) float Tpart[4][8][64];    // per-wave T partials
    __shared__ __align__(16) float Tred[8][64];        // reduced T
    __shared__ __align__(16) unsigned short Hn[8][64]; // high, bf16

    const int t = threadIdx.x, lane = t & 63, g = t >> 6, b = blockIdx.x;
    const int sl = seq_len[b];
    const unsigned short* lnb = ln + ((size_t)b << 15);

    // ---- masked softmax, wave-local; wave g owns k=g, g+4 -----------------
    #pragma unroll
    for (int kk = 0; kk < 2; ++kk) {
        const int k = g + (kk << 2);
        float v[8];
        float mx = NEG_FILL;
        #pragma unroll
        for (int j = 0; j < 8; ++j) {
            int l = lane + (j << 6);
            v[j] = (l < sl) ? Bcur[(k << 9) + l] : NEG_FILL;
            mx = fmaxf(mx, v[j]);
        }
        #pragma unroll
        for (int off = 32; off; off >>= 1) mx = fmaxf(mx, __shfl_xor(mx, off));
        float s = 0.f;
        #pragma unroll
        for (int j = 0; j < 8; ++j) { v[j] = expf(v[j] - mx); s += v[j]; }
        #pragma unroll
        for (int off = 32; off; off >>= 1) s += __shfl_xor(s, off);
        const float inv = 1.0f / s;
        #pragma unroll
        for (int j = 0; j < 8; ++j) WsT[lane + (j << 6)][k] = v[j] * inv;
    }
    __syncthreads();

    // ---- T-phase: lane = (row-in-quad rq, o-quad oq); 4 rows per instr ----
    const int oq = lane & 15, rq = lane >> 4;
    float Ta[8][4];
    #pragma unroll
    for (int k = 0; k < 8; ++k)
        { Ta[k][0] = 0.f; Ta[k][1] = 0.f; Ta[k][2] = 0.f; Ta[k][3] = 0.f; }
    {
        const int l0 = g << 7;
        #pragma unroll 4
        for (int it = 0; it < 32; ++it) {
            const int l = l0 + (it << 2) + rq;
            const uint2 u = *(const uint2*)&lnb[(l << 6) + (oq << 2)];
            const float x0 = __uint_as_float(u.x << 16);
            const float x1 = __uint_as_float(u.x & 0xFFFF0000u);
            const float x2 = __uint_as_float(u.y << 16);
            const float x3 = __uint_as_float(u.y & 0xFFFF0000u);
            const float4 wa = *(const float4*)&WsT[l][0];
            const float4 wb = *(const float4*)&WsT[l][4];
            const float wk[8] = {wa.x, wa.y, wa.z, wa.w, wb.x, wb.y, wb.z, wb.w};
            #pragma unroll
            for (int k = 0; k < 8; ++k) {
                Ta[k][0] = fmaf(wk[k], x0, Ta[k][0]);
                Ta[k][1] = fmaf(wk[k], x1, Ta[k][1]);
                Ta[k][2] = fmaf(wk[k], x2, Ta[k][2]);
                Ta[k][3] = fmaf(wk[k], x3, Ta[k][3]);
            }
        }
    }
    // reduce over the 4 row-groups (lanes oq, oq+16, oq+32, oq+48)
    #pragma unroll
    for (int k = 0; k < 8; ++k)
        #pragma unroll
        for (int j = 0; j < 4; ++j) {
            float v = Ta[k][j];
            v += __shfl_xor(v, 16);
            v += __shfl_xor(v, 32);
            Ta[k][j] = v;
        }
    if (rq == 0) {
        #pragma unroll
        for (int k = 0; k < 8; ++k)
            *(float4*)&Tpart[g][k][oq << 2] =
                make_float4(Ta[k][0], Ta[k][1], Ta[k][2], Ta[k][3]);
    }
    __syncthreads();

    // ---- cross-wave reduce: 512 values, 256 threads x 2 -------------------
    #pragma unroll
    for (int idx = t; idx < 512; idx += 256) {
        float s = (&Tpart[0][0][0])[idx] + (&Tpart[1][0][0])[idx]
                + (&Tpart[2][0][0])[idx] + (&Tpart[3][0][0])[idx];
        (&Tred[0][0])[idx] = s;
    }
    __syncthreads();

    // ---- squash over K; thread (g, lane=o) owns k=g, g+4 ------------------
    float sq = 0.f;
    #pragma unroll
    for (int k = 0; k < 8; ++k) { float x = Tred[k][lane]; sq = fmaf(x, x, sq); }
    const float scale = sq / (1.0f + sq) / sqrtf(sq + 1e-9f);
    const float hf0 = scale * Tred[g][lane];
    const float hf1 = scale * Tred[g + 4][lane];

    if (last) {
        out[(((size_t)b * 8 + g)     << 6) + lane] = hf0;
        out[(((size_t)b * 8 + g + 4) << 6) + lane] = hf1;
        return;
    }
    Hn[g][lane]     = f2bf(hf0);
    Hn[g + 4][lane] = f2bf(hf1);
    __syncthreads();

    // ---- delta = high @ ln^T via MFMA 16x16x32 bf16 -----------------------
    // A[m=k_c][k=o]: lane m = lane&15 (valid <8), o = oh*32 + q*8 + j.
    const int m = lane & 15, q = lane >> 4;
    short8 afrag[2];
    #pragma unroll
    for (int oh = 0; oh < 2; ++oh) {
        short8 f = {0, 0, 0, 0, 0, 0, 0, 0};
        if (m < 8) f = *(const short8*)&Hn[m][oh * 32 + q * 8];
        afrag[oh] = f;
    }
    // B[k=o][n=l]: lane n = m -> row lt+m of ln, contiguous o's = one 16B load
    #pragma unroll 2
    for (int tt = 0; tt < 8; ++tt) {
        const int lt = (g << 7) + (tt << 4);
        floatx4 acc = {0.f, 0.f, 0.f, 0.f};
        #pragma unroll
        for (int oh = 0; oh < 2; ++oh) {
            const short8 bfrag =
                *(const short8*)&lnb[((lt + m) << 6) + oh * 32 + q * 8];
            acc = __builtin_amdgcn_mfma_f32_16x16x32_bf16(afrag[oh], bfrag, acc, 0, 0, 0);
        }
        // C: col = m (l-within-tile), row = q*4 + r (k_c); valid rows < 8
        if (q < 2) {
            #pragma unroll
            for (int r = 0; r < 4; ++r)
                atomicAdd(&Bnext[(q * 4 + r) * 512 + lt + m], acc[r]);
        }
    }
}

// ===========================================================================
// Fallback (round-4 verified path) — used only if ws_size is too small.
__global__ __launch_bounds__(256, 4) void k_route(
    const float* __restrict__ low, const float* __restrict__ S,
    const float* __restrict__ Bcur, float* __restrict__ Bnext,
    const int* __restrict__ seq_len, float* __restrict__ out, int last)
{
    __shared__ float smemA[64 * 65];
    __shared__ float Spad[64][65];
    __shared__ float GT[64][8];
    __shared__ float Tred[8][64];
    float* WsT = smemA;
    float (*Tpart)[8][64] = (float (*)[8][64])smemA;
    float (*tile)[65]     = (float (*)[65])smemA;

    const int t = threadIdx.x, o = t & 63, g = t >> 6, b = blockIdx.x;
    const int sl = seq_len[b];
    const float* lowb = low + ((size_t)b << 15);

    #pragma unroll
    for (int i = 0; i < 16; ++i) {
        int idx = t + (i << 8);
        Spad[idx >> 6][idx & 63] = S[idx];
    }
    #pragma unroll
    for (int kk = 0; kk < 2; ++kk) {
        const int k = g + (kk << 2);
        float v[8];
        float mx = NEG_FILL;
        #pragma unroll
        for (int j = 0; j < 8; ++j) {
            int l = o + (j << 6);
            v[j] = (l < sl) ? Bcur[(k << 9) + l] : NEG_FILL;
            mx = fmaxf(mx, v[j]);
        }
        #pragma unroll
        for (int off = 32; off; off >>= 1) mx = fmaxf(mx, __shfl_xor(mx, off));
        float s = 0.f;
        #pragma unroll
        for (int j = 0; j < 8; ++j) { v[j] = expf(v[j] - mx); s += v[j]; }
        #pragma unroll
        for (int off = 32; off; off >>= 1) s += __shfl_xor(s, off);
        const float inv = 1.0f / s;
        #pragma unroll
        for (int j = 0; j < 8; ++j) WsT[((o + (j << 6)) << 3) + k] = v[j] * inv;
    }
    __syncthreads();

    float Ta[8];
    #pragma unroll
    for (int k = 0; k < 8; ++k) Ta[k] = 0.f;
    {
        const int l0 = g << 7;
        #pragma unroll 4
        for (int i = 0; i < 128; ++i) {
            const int l = l0 + i;
            const float x = lowb[(l << 6) + o];
            const float4 wa = *(const float4*)&WsT[(l << 3)];
            const float4 wb = *(const float4*)&WsT[(l << 3) + 4];
            Ta[0] = fmaf(wa.x, x, Ta[0]); Ta[1] = fmaf(wa.y, x, Ta[1]);
            Ta[2] = fmaf(wa.z, x, Ta[2]); Ta[3] = fmaf(wa.w, x, Ta[3]);
            Ta[4] = fmaf(wb.x, x, Ta[4]); Ta[5] = fmaf(wb.y, x, Ta[5]);
            Ta[6] = fmaf(wb.z, x, Ta[6]); Ta[7] = fmaf(wb.w, x, Ta[7]);
        }
    }
    __syncthreads();
    #pragma unroll
    for (int k = 0; k < 8; ++k) Tpart[g][k][o] = Ta[k];
    __syncthreads();

    float h0 = 0.f, h1 = 0.f;
    #pragma unroll
    for (int gg = 0; gg < 4; ++gg) { h0 += Tpart[gg][g][o]; h1 += Tpart[gg][g + 4][o]; }
    Tred[g][o] = h0; Tred[g + 4][o] = h1;
    __syncthreads();

    float hp0 = 0.f, hp1 = 0.f;
    #pragma unroll
    for (int d = 0; d < 64; ++d) {
        const float sv = Spad[d][o];
        hp0 = fmaf(Tred[g][d], sv, hp0);
        hp1 = fmaf(Tred[g + 4][d], sv, hp1);
    }
    __syncthreads();
    Tred[g][o] = hp0; Tred[g + 4][o] = hp1;
    __syncthreads();

    float sq = 0.f;
    #pragma unroll
    for (int k = 0; k < 8; ++k) { float x = Tred[k][o]; sq = fmaf(x, x, sq); }
    const float scale = sq / (1.0f + sq) / sqrtf(sq + 1e-9f);
    const float hf0 = scale * hp0;
    const float hf1 = scale * hp1;

    if (last) {
        out[(((size_t)b * 8 + g)     << 6) + o] = hf0;
        out[(((size_t)b * 8 + g + 4) << 6) + o] = hf1;
        return;
    }
    __syncthreads();
    Tred[g][o] = hf0; Tred[g + 4][o] = hf1;
    __syncthreads();

    float g0 = 0.f, g1 = 0.f;
    #pragma unroll
    for (int oo = 0; oo < 64; ++oo) {
        const float sv = Spad[o][oo];
        g0 = fmaf(Tred[g][oo], sv, g0);
        g1 = fmaf(Tred[g + 4][oo], sv, g1);
    }
    GT[o][g] = g0; GT[o][g + 4] = g1;
    __syncthreads();

    for (int c = 0; c < 8; ++c) {
        const int lc = c << 6;
        #pragma unroll
        for (int r = 0; r < 16; ++r) {
            const int lr = (g << 4) + r;
            tile[lr][o] = lowb[((lc + lr) << 6) + o];
        }
        __syncthreads();
        float a0 = 0.f, a1 = 0.f;
        #pragma unroll
        for (int d = 0; d < 64; ++d) {
            const float x = tile[o][d];
            a0 = fmaf(GT[d][g], x, a0);
            a1 = fmaf(GT[d][g + 4], x, a1);
        }
        atomicAdd(&Bnext[(g << 9) + lc + o], a0);
        atomicAdd(&Bnext[((g + 4) << 9) + lc + o], a1);
        __syncthreads();
    }
}

// ---------------------------------------------------------------------------
extern "C" void kernel_launch(void* const* d_in, const int* in_sizes, int n_in,
                              void* d_out, int out_size, void* d_ws, size_t ws_size,
                              hipStream_t stream) {
    const float* low   = (const float*)d_in[0];   // [1024,512,64]
    const float* Binit = (const float*)d_in[1];   // [1,8,512]
    const float* S     = (const float*)d_in[2];   // [64,64]
    const int*   seq   = (const int*)d_in[3];     // [1024,1]
    float* outp = (float*)d_out;                  // [1024,8,64] f32

    const size_t LN_BYTES = (size_t)1024 * 512 * 64 * 2;   // 67.1 MB bf16
    const size_t NEED = LN_BYTES + 2 * 4096 * sizeof(float);

    if (ws_size >= NEED) {
        unsigned short* lnw = (unsigned short*)d_ws;
        float* B0 = (float*)((char*)d_ws + LN_BYTES);
        float* B1 = B0 + 4096;

        k_copy4k<<<16, 256, 0, stream>>>(Binit, B0);
        k_ln<<<1024, 256, 0, stream>>>(low, S, lnw);

        k_copy4k<<<16, 256, 0, stream>>>(B0, B1);
        k_route2<<<1024, 256, 0, stream>>>(lnw, B0, B1, seq, outp, 0);

        k_copy4k<<<16, 256, 0, stream>>>(B1, B0);
        k_route2<<<1024, 256, 0, stream>>>(lnw, B1, B0, seq, outp, 0);

        k_route2<<<1024, 256, 0, stream>>>(lnw, B0, nullptr, seq, outp, 1);
    } else {
        // fallback: round-4 verified path (ws >= 32 KB)
        float* B0 = (float*)d_ws;
        float* B1 = B0 + 4096;
        k_copy4k<<<16, 256, 0, stream>>>(Binit, B0);
        k_copy4k<<<16, 256, 0, stream>>>(B0, B1);
        k_route<<<1024, 256, 0, stream>>>(low, S, B0, B1, seq, outp, 0);
        k_copy4k<<<16, 256, 0, stream>>>(B1, B0);
        k_route<<<1024, 256, 0, stream>>>(low, S, B1, B0, seq, outp, 0);
        k_route<<<1024, 256, 0, stream>>>(low, S, B0, nullptr, seq, outp, 1);
    }
}

// Round 6
// 289.932 us; speedup vs baseline: 26.0487x; 1.1542x over previous
//
#include <hip/hip_runtime.h>

#define NEG_FILL (-65535.0f)   // -2^16 + 1, the mask fill value
#define NSLOT 16

typedef __attribute__((ext_vector_type(8))) short  short8;   // 8 x bf16 bits
typedef __attribute__((ext_vector_type(4))) float  floatx4;  // mfma acc

__device__ inline unsigned short f2bf(float f) {             // f32 -> bf16 RNE
    unsigned u = __float_as_uint(f);
    u += 0x7FFFu + ((u >> 16) & 1u);
    return (unsigned short)(u >> 16);
}

// ---------------------------------------------------------------------------
// init: B0 = Binit (first 4096 ids), slots = 0 (65536 ids). grid = 256 x 256.
__global__ __launch_bounds__(256) void k_init(const float* __restrict__ Binit,
                                              float* __restrict__ B0,
                                              float* __restrict__ slots) {
    int i = blockIdx.x * 256 + threadIdx.x;
    slots[i] = 0.f;
    if (i < 4096) B0[i] = Binit[i];
}

// ---------------------------------------------------------------------------
// Bnext = Bcur + sum_s slots[s]; re-zero slots. grid = 16 x 256.
__global__ __launch_bounds__(256) void k_bred(const float* __restrict__ Bcur,
                                              float* __restrict__ Bnext,
                                              float* __restrict__ slots) {
    int i = blockIdx.x * 256 + threadIdx.x;       // 0..4095
    float s = Bcur[i];
    #pragma unroll
    for (int j = 0; j < NSLOT; ++j) {
        s += slots[j * 4096 + i];
        slots[j * 4096 + i] = 0.f;
    }
    Bnext[i] = s;
}

// ---------------------------------------------------------------------------
// Precompute ln[b,l,o] = sum_d low[b,l,d]*S[d,o], stored bf16. MFMA 16x16x32.
__global__ __launch_bounds__(256, 4) void k_ln(
    const float* __restrict__ low,       // [1024,512,64]
    const float* __restrict__ S,         // [64,64]
    unsigned short* __restrict__ ln)     // [1024,512,64] bf16 out
{
    const int t = threadIdx.x, lane = t & 63, g = t >> 6, b = blockIdx.x;
    const int m = lane & 15, q = lane >> 4;
    const float* lowb = low + ((size_t)b << 15);
    unsigned short* lnb = ln + ((size_t)b << 15);

    // B-frags for S: B[k=d][n=o]: lane col o = nt*16+m, d = dh*32 + q*8 + j.
    short8 sfrag[4][2];
    #pragma unroll
    for (int nt = 0; nt < 4; ++nt)
        #pragma unroll
        for (int dh = 0; dh < 2; ++dh) {
            short8 f;
            #pragma unroll
            for (int j = 0; j < 8; ++j) {
                int d = dh * 32 + q * 8 + j;
                f[j] = (short)f2bf(S[(d << 6) + nt * 16 + m]);
            }
            sfrag[nt][dh] = f;
        }

    #pragma unroll 2
    for (int tt = 0; tt < 8; ++tt) {
        const int lt = (g << 7) + (tt << 4);
        short8 afrag[2];   // A[m=l][k=d]
        #pragma unroll
        for (int dh = 0; dh < 2; ++dh) {
            const float4* p =
                (const float4*)&lowb[((lt + m) << 6) + dh * 32 + q * 8];
            float4 x0 = p[0], x1 = p[1];
            short8 f;
            f[0] = (short)f2bf(x0.x); f[1] = (short)f2bf(x0.y);
            f[2] = (short)f2bf(x0.z); f[3] = (short)f2bf(x0.w);
            f[4] = (short)f2bf(x1.x); f[5] = (short)f2bf(x1.y);
            f[6] = (short)f2bf(x1.z); f[7] = (short)f2bf(x1.w);
            afrag[dh] = f;
        }
        #pragma unroll
        for (int nt = 0; nt < 4; ++nt) {
            floatx4 acc = {0.f, 0.f, 0.f, 0.f};
            acc = __builtin_amdgcn_mfma_f32_16x16x32_bf16(afrag[0], sfrag[nt][0], acc, 0, 0, 0);
            acc = __builtin_amdgcn_mfma_f32_16x16x32_bf16(afrag[1], sfrag[nt][1], acc, 0, 0, 0);
            #pragma unroll
            for (int r = 0; r < 4; ++r)
                lnb[((size_t)(lt + q * 4 + r) << 6) + nt * 16 + m] = f2bf(acc[r]);
        }
    }
}

// ---------------------------------------------------------------------------
// One routing iteration on precomputed ln (bf16):
//   W = softmax(mask ? Bcur : NEG); T = W @ ln  (== high_pre);
//   high = squash_overK(T); delta = high @ ln^T -> atomicAdd into slot.
__global__ __launch_bounds__(256, 4) void k_route2(
    const unsigned short* __restrict__ ln,   // [1024,512,64] bf16
    const float* __restrict__ Bcur,          // [8,512]
    float* __restrict__ slots,               // [NSLOT][8,512], if !last
    const int* __restrict__ seq_len,         // [1024]
    float* __restrict__ out,                 // [1024,8,64] f32, if last
    int last)
{
    __shared__ __align__(16) float WsT[512][8];        // W transposed
    __shared__ __align__(16) float Tpart[4][8][64];    // per-wave T partials
    __shared__ __align__(16) float Tred[8][64];        // reduced T
    __shared__ __align__(16) unsigned short Hn[8][64]; // high, bf16

    const int t = threadIdx.x, lane = t & 63, g = t >> 6, b = blockIdx.x;
    const int sl = seq_len[b];
    const unsigned short* lnb = ln + ((size_t)b << 15);

    // ---- masked softmax, wave-local; wave g owns k=g, g+4 -----------------
    #pragma unroll
    for (int kk = 0; kk < 2; ++kk) {
        const int k = g + (kk << 2);
        float v[8];
        float mx = NEG_FILL;
        #pragma unroll
        for (int j = 0; j < 8; ++j) {
            int l = lane + (j << 6);
            v[j] = (l < sl) ? Bcur[(k << 9) + l] : NEG_FILL;
            mx = fmaxf(mx, v[j]);
        }
        #pragma unroll
        for (int off = 32; off; off >>= 1) mx = fmaxf(mx, __shfl_xor(mx, off));
        float s = 0.f;
        #pragma unroll
        for (int j = 0; j < 8; ++j) { v[j] = expf(v[j] - mx); s += v[j]; }
        #pragma unroll
        for (int off = 32; off; off >>= 1) s += __shfl_xor(s, off);
        const float inv = 1.0f / s;
        #pragma unroll
        for (int j = 0; j < 8; ++j) WsT[lane + (j << 6)][k] = v[j] * inv;
    }
    __syncthreads();

    // ---- T-phase: lane (oq = 4 cols, rq = row-in-group); 4 rows / iter ----
    const int oq = lane & 15, rq = lane >> 4;
    floatx4 Tacc[8];
    #pragma unroll
    for (int k = 0; k < 8; ++k) Tacc[k] = (floatx4){0.f, 0.f, 0.f, 0.f};
    {
        const int l0 = g << 7;
        #pragma unroll 2
        for (int it = 0; it < 32; ++it) {
            const int l = l0 + (it << 2) + rq;
            const uint2 u = *(const uint2*)&lnb[(l << 6) + (oq << 2)];
            const float x0 = __uint_as_float(u.x << 16);
            const float x1 = __uint_as_float(u.x & 0xFFFF0000u);
            const float x2 = __uint_as_float(u.y << 16);
            const float x3 = __uint_as_float(u.y & 0xFFFF0000u);
            const float4 wa = *(const float4*)&WsT[l][0];
            const float4 wb = *(const float4*)&WsT[l][4];
#define TROW(K, WV)                                          \
            Tacc[K][0] = fmaf(WV, x0, Tacc[K][0]);           \
            Tacc[K][1] = fmaf(WV, x1, Tacc[K][1]);           \
            Tacc[K][2] = fmaf(WV, x2, Tacc[K][2]);           \
            Tacc[K][3] = fmaf(WV, x3, Tacc[K][3]);
            TROW(0, wa.x) TROW(1, wa.y) TROW(2, wa.z) TROW(3, wa.w)
            TROW(4, wb.x) TROW(5, wb.y) TROW(6, wb.z) TROW(7, wb.w)
#undef TROW
        }
    }
    // reduce over the 4 row-groups (lanes oq, oq+16, oq+32, oq+48)
    #pragma unroll
    for (int k = 0; k < 8; ++k)
        #pragma unroll
        for (int j = 0; j < 4; ++j) {
            float v = Tacc[k][j];
            v += __shfl_xor(v, 16);
            v += __shfl_xor(v, 32);
            Tacc[k][j] = v;
        }
    if (rq == 0) {
        #pragma unroll
        for (int k = 0; k < 8; ++k)
            *(float4*)&Tpart[g][k][oq << 2] =
                make_float4(Tacc[k][0], Tacc[k][1], Tacc[k][2], Tacc[k][3]);
    }
    __syncthreads();

    // ---- cross-wave reduce: 512 values, 256 threads x 2 -------------------
    #pragma unroll
    for (int idx = t; idx < 512; idx += 256) {
        float s = (&Tpart[0][0][0])[idx] + (&Tpart[1][0][0])[idx]
                + (&Tpart[2][0][0])[idx] + (&Tpart[3][0][0])[idx];
        (&Tred[0][0])[idx] = s;
    }
    __syncthreads();

    // ---- squash over K; thread (g, lane=o) owns k=g, g+4 ------------------
    float sq = 0.f;
    #pragma unroll
    for (int k = 0; k < 8; ++k) { float x = Tred[k][lane]; sq = fmaf(x, x, sq); }
    const float scale = sq / (1.0f + sq) / sqrtf(sq + 1e-9f);
    const float hf0 = scale * Tred[g][lane];
    const float hf1 = scale * Tred[g + 4][lane];

    if (last) {
        out[(((size_t)b * 8 + g)     << 6) + lane] = hf0;
        out[(((size_t)b * 8 + g + 4) << 6) + lane] = hf1;
        return;
    }
    Hn[g][lane]     = f2bf(hf0);
    Hn[g + 4][lane] = f2bf(hf1);
    __syncthreads();

    // ---- delta = high @ ln^T via MFMA 16x16x32 bf16 -----------------------
    float* slot = slots + ((b & (NSLOT - 1)) << 12);   // this block's slot
    const int m = lane & 15, q = lane >> 4;
    short8 afrag[2];                       // A[m=k_c][k=o], valid m < 8
    #pragma unroll
    for (int oh = 0; oh < 2; ++oh) {
        short8 f = {0, 0, 0, 0, 0, 0, 0, 0};
        if (m < 8) f = *(const short8*)&Hn[m][oh * 32 + q * 8];
        afrag[oh] = f;
    }
    #pragma unroll 2
    for (int tt = 0; tt < 8; ++tt) {
        const int lt = (g << 7) + (tt << 4);
        floatx4 acc = {0.f, 0.f, 0.f, 0.f};
        #pragma unroll
        for (int oh = 0; oh < 2; ++oh) {
            const short8 bfrag =
                *(const short8*)&lnb[((lt + m) << 6) + oh * 32 + q * 8];
            acc = __builtin_amdgcn_mfma_f32_16x16x32_bf16(afrag[oh], bfrag, acc, 0, 0, 0);
        }
        if (q < 2) {
            #pragma unroll
            for (int r = 0; r < 4; ++r)
                atomicAdd(&slot[(q * 4 + r) * 512 + lt + m], acc[r]);
        }
    }
}

// ===========================================================================
// Fallback (round-4 verified path) — used only if ws_size is too small.
__global__ __launch_bounds__(256) void k_copy4k(const float* __restrict__ src,
                                                float* __restrict__ dst) {
    int i = blockIdx.x * 256 + threadIdx.x;
    dst[i] = src[i];
}

__global__ __launch_bounds__(256, 4) void k_route(
    const float* __restrict__ low, const float* __restrict__ S,
    const float* __restrict__ Bcur, float* __restrict__ Bnext,
    const int* __restrict__ seq_len, float* __restrict__ out, int last)
{
    __shared__ float smemA[64 * 65];
    __shared__ float Spad[64][65];
    __shared__ float GT[64][8];
    __shared__ float Tred[8][64];
    float* WsT = smemA;
    float (*Tpart)[8][64] = (float (*)[8][64])smemA;
    float (*tile)[65]     = (float (*)[65])smemA;

    const int t = threadIdx.x, o = t & 63, g = t >> 6, b = blockIdx.x;
    const int sl = seq_len[b];
    const float* lowb = low + ((size_t)b << 15);

    #pragma unroll
    for (int i = 0; i < 16; ++i) {
        int idx = t + (i << 8);
        Spad[idx >> 6][idx & 63] = S[idx];
    }
    #pragma unroll
    for (int kk = 0; kk < 2; ++kk) {
        const int k = g + (kk << 2);
        float v[8];
        float mx = NEG_FILL;
        #pragma unroll
        for (int j = 0; j < 8; ++j) {
            int l = o + (j << 6);
            v[j] = (l < sl) ? Bcur[(k << 9) + l] : NEG_FILL;
            mx = fmaxf(mx, v[j]);
        }
        #pragma unroll
        for (int off = 32; off; off >>= 1) mx = fmaxf(mx, __shfl_xor(mx, off));
        float s = 0.f;
        #pragma unroll
        for (int j = 0; j < 8; ++j) { v[j] = expf(v[j] - mx); s += v[j]; }
        #pragma unroll
        for (int off = 32; off; off >>= 1) s += __shfl_xor(s, off);
        const float inv = 1.0f / s;
        #pragma unroll
        for (int j = 0; j < 8; ++j) WsT[((o + (j << 6)) << 3) + k] = v[j] * inv;
    }
    __syncthreads();

    float Ta[8];
    #pragma unroll
    for (int k = 0; k < 8; ++k) Ta[k] = 0.f;
    {
        const int l0 = g << 7;
        #pragma unroll 4
        for (int i = 0; i < 128; ++i) {
            const int l = l0 + i;
            const float x = lowb[(l << 6) + o];
            const float4 wa = *(const float4*)&WsT[(l << 3)];
            const float4 wb = *(const float4*)&WsT[(l << 3) + 4];
            Ta[0] = fmaf(wa.x, x, Ta[0]); Ta[1] = fmaf(wa.y, x, Ta[1]);
            Ta[2] = fmaf(wa.z, x, Ta[2]); Ta[3] = fmaf(wa.w, x, Ta[3]);
            Ta[4] = fmaf(wb.x, x, Ta[4]); Ta[5] = fmaf(wb.y, x, Ta[5]);
            Ta[6] = fmaf(wb.z, x, Ta[6]); Ta[7] = fmaf(wb.w, x, Ta[7]);
        }
    }
    __syncthreads();
    #pragma unroll
    for (int k = 0; k < 8; ++k) Tpart[g][k][o] = Ta[k];
    __syncthreads();

    float h0 = 0.f, h1 = 0.f;
    #pragma unroll
    for (int gg = 0; gg < 4; ++gg) { h0 += Tpart[gg][g][o]; h1 += Tpart[gg][g + 4][o]; }
    Tred[g][o] = h0; Tred[g + 4][o] = h1;
    __syncthreads();

    float hp0 = 0.f, hp1 = 0.f;
    #pragma unroll
    for (int d = 0; d < 64; ++d) {
        const float sv = Spad[d][o];
        hp0 = fmaf(Tred[g][d], sv, hp0);
        hp1 = fmaf(Tred[g + 4][d], sv, hp1);
    }
    __syncthreads();
    Tred[g][o] = hp0; Tred[g + 4][o] = hp1;
    __syncthreads();

    float sq = 0.f;
    #pragma unroll
    for (int k = 0; k < 8; ++k) { float x = Tred[k][o]; sq = fmaf(x, x, sq); }
    const float scale = sq / (1.0f + sq) / sqrtf(sq + 1e-9f);
    const float hf0 = scale * hp0;
    const float hf1 = scale * hp1;

    if (last) {
        out[(((size_t)b * 8 + g)     << 6) + o] = hf0;
        out[(((size_t)b * 8 + g + 4) << 6) + o] = hf1;
        return;
    }
    __syncthreads();
    Tred[g][o] = hf0; Tred[g + 4][o] = hf1;
    __syncthreads();

    float g0 = 0.f, g1 = 0.f;
    #pragma unroll
    for (int oo = 0; oo < 64; ++oo) {
        const float sv = Spad[o][oo];
        g0 = fmaf(Tred[g][oo], sv, g0);
        g1 = fmaf(Tred[g + 4][oo], sv, g1);
    }
    GT[o][g] = g0; GT[o][g + 4] = g1;
    __syncthreads();

    for (int c = 0; c < 8; ++c) {
        const int lc = c << 6;
        #pragma unroll
        for (int r = 0; r < 16; ++r) {
            const int lr = (g << 4) + r;
            tile[lr][o] = lowb[((lc + lr) << 6) + o];
        }
        __syncthreads();
        float a0 = 0.f, a1 = 0.f;
        #pragma unroll
        for (int d = 0; d < 64; ++d) {
            const float x = tile[o][d];
            a0 = fmaf(GT[d][g], x, a0);
            a1 = fmaf(GT[d][g + 4], x, a1);
        }
        atomicAdd(&Bnext[(g << 9) + lc + o], a0);
        atomicAdd(&Bnext[((g + 4) << 9) + lc + o], a1);
        __syncthreads();
    }
}

// ---------------------------------------------------------------------------
extern "C" void kernel_launch(void* const* d_in, const int* in_sizes, int n_in,
                              void* d_out, int out_size, void* d_ws, size_t ws_size,
                              hipStream_t stream) {
    const float* low   = (const float*)d_in[0];   // [1024,512,64]
    const float* Binit = (const float*)d_in[1];   // [1,8,512]
    const float* S     = (const float*)d_in[2];   // [64,64]
    const int*   seq   = (const int*)d_in[3];     // [1024,1]
    float* outp = (float*)d_out;                  // [1024,8,64] f32

    const size_t LN_BYTES   = (size_t)1024 * 512 * 64 * 2;       // 67.1 MB
    const size_t SLOT_BYTES = (size_t)NSLOT * 4096 * sizeof(float);
    const size_t NEED = LN_BYTES + SLOT_BYTES + 2 * 4096 * sizeof(float);

    if (ws_size >= NEED) {
        unsigned short* lnw = (unsigned short*)d_ws;
        float* slots = (float*)((char*)d_ws + LN_BYTES);
        float* B0 = slots + (size_t)NSLOT * 4096;
        float* B1 = B0 + 4096;

        k_init<<<256, 256, 0, stream>>>(Binit, B0, slots);     // B0=Binit, slots=0
        k_ln<<<1024, 256, 0, stream>>>(low, S, lnw);

        k_route2<<<1024, 256, 0, stream>>>(lnw, B0, slots, seq, outp, 0);
        k_bred<<<16, 256, 0, stream>>>(B0, B1, slots);         // B1 = B0 + Σ, zero

        k_route2<<<1024, 256, 0, stream>>>(lnw, B1, slots, seq, outp, 0);
        k_bred<<<16, 256, 0, stream>>>(B1, B0, slots);         // B0 = B1 + Σ, zero

        k_route2<<<1024, 256, 0, stream>>>(lnw, B0, nullptr, seq, outp, 1);
    } else {
        // fallback: round-4 verified path (ws >= 32 KB)
        float* B0 = (float*)d_ws;
        float* B1 = B0 + 4096;
        k_copy4k<<<16, 256, 0, stream>>>(Binit, B0);
        k_copy4k<<<16, 256, 0, stream>>>(B0, B1);
        k_route<<<1024, 256, 0, stream>>>(low, S, B0, B1, seq, outp, 0);
        k_copy4k<<<16, 256, 0, stream>>>(B1, B0);
        k_route<<<1024, 256, 0, stream>>>(low, S, B1, B0, seq, outp, 0);
        k_route<<<1024, 256, 0, stream>>>(low, S, B0, nullptr, seq, outp, 1);
    }
}